// Round 1
// 1487.739 us; speedup vs baseline: 1.1325x; 1.1325x over previous
//
#include <hip/hip_runtime.h>
#include <math.h>

#define DIM 256
#define VAL_DIM 300

typedef __attribute__((ext_vector_type(8))) short short8;
typedef __attribute__((ext_vector_type(4))) float fx4;

__device__ __forceinline__ short f2bf(float x) {
    unsigned u = __float_as_uint(x);
    unsigned r = (u + 0x7fff + ((u >> 16) & 1)) >> 16;
    return (short)r;
}
__device__ __forceinline__ float bf2f(short h) {
    return __uint_as_float(((unsigned)(unsigned short)h) << 16);
}

// ---------------- split B (weights) into MFMA B-fragment order, hi/lo bf16 ----------------
// B-frag layout: lane holds B[k = kt*32 + (lane>>4)*8 + j][n = nt*16 + (lane&15)], j=0..7
// storage: frag_idx = nt*(Kp/32) + kt; addr = frag_idx*512 + lane*8 + j
__global__ void k_split_b(const float* __restrict__ W, short* __restrict__ Bhi,
                          short* __restrict__ Blo, int Kreal, int Kp, int Ncols) {
    int idx = blockIdx.x * 256 + threadIdx.x;
    int total = (Ncols / 16) * (Kp / 32) * 64;
    if (idx >= total) return;
    int lane = idx & 63;
    int kt = (idx >> 6) % (Kp / 32);
    int nt = (idx >> 6) / (Kp / 32);
    int n = nt * 16 + (lane & 15);
    int kbase = kt * 32 + ((lane >> 4) & 3) * 8;
    short h[8], l[8];
#pragma unroll
    for (int j = 0; j < 8; ++j) {
        int k = kbase + j;
        float x = (k < Kreal) ? W[(size_t)k * Ncols + n] : 0.f;
        short hh = f2bf(x);
        float r = x - bf2f(hh);
        h[j] = hh;
        l[j] = f2bf(r);
    }
    size_t base = (size_t)idx * 8;
#pragma unroll
    for (int j = 0; j < 8; ++j) { Bhi[base + j] = h[j]; Blo[base + j] = l[j]; }
}

// ---------------- split-bf16 MFMA GEMM: Out = A(MxK fp32) @ B(KxN via frags) ----------------
// MODE 0: Out[row*ldout+col] = acc          (val_proj)
// MODE 1: Out += relu(acc + bias)           (gcn layer 1)
// MODE 2: Out += (acc + bias)               (gcn layer 2)
template <int MODE>
__global__ void k_gemm(const float* __restrict__ A, const short* __restrict__ Bhi,
                       const short* __restrict__ Blo, const float* __restrict__ bias,
                       float* __restrict__ Out, int M, int K, int Kp, int ldout) {
    __shared__ short Ah[8 * 512];  // 8 tiles of (64 lanes x 8 bf16) = 8KB
    __shared__ short Al[8 * 512];
    const int m0 = blockIdx.x * 64;
    const int n0 = blockIdx.y * 64;
    const int tid = threadIdx.x;
    const int wave = tid >> 6;
    const int lane = tid & 63;
    const int wm = (wave >> 1) * 2;  // mtile base (16-row units) for this wave
    const int wn = (wave & 1) * 2;   // ntile base
    fx4 acc[2][2] = {};

    for (int pk = 0; pk < Kp; pk += 64) {
        // ---- stage A panel (64 rows x 64 k) as hi/lo fragments ----
#pragma unroll
        for (int q = 0; q < 2; ++q) {
            int ss = tid + 256 * q;     // 0..511
            int mt = ss >> 7;           // 0..3
            int ks = (ss >> 6) & 1;     // 0..1
            int ln = ss & 63;
            int row = m0 + mt * 16 + (ln & 15);
            int kk = pk + ks * 32 + ((ln >> 4) & 3) * 8;
            float v[8];
            if (row < M && kk + 8 <= K) {
                fx4 u0 = *(const fx4*)&A[(size_t)row * K + kk];
                fx4 u1 = *(const fx4*)&A[(size_t)row * K + kk + 4];
                v[0] = u0[0]; v[1] = u0[1]; v[2] = u0[2]; v[3] = u0[3];
                v[4] = u1[0]; v[5] = u1[1]; v[6] = u1[2]; v[7] = u1[3];
            } else {
#pragma unroll
                for (int j = 0; j < 8; ++j)
                    v[j] = (row < M && kk + j < K) ? A[(size_t)row * K + kk + j] : 0.f;
            }
            short8 h8, l8;
#pragma unroll
            for (int j = 0; j < 8; ++j) {
                short hh = f2bf(v[j]);
                h8[j] = hh;
                l8[j] = f2bf(v[j] - bf2f(hh));
            }
            *(short8*)&Ah[(mt * 2 + ks) * 512 + ln * 8] = h8;
            *(short8*)&Al[(mt * 2 + ks) * 512 + ln * 8] = l8;
        }
        __syncthreads();
        // ---- compute: 2 MFMA k-steps of 32 ----
#pragma unroll
        for (int ks = 0; ks < 2; ++ks) {
            int kglob = pk + ks * 32;
            short8 ah[2], al[2], bh[2], bl[2];
#pragma unroll
            for (int t = 0; t < 2; ++t) {
                ah[t] = *(short8*)&Ah[((wm + t) * 2 + ks) * 512 + lane * 8];
                al[t] = *(short8*)&Al[((wm + t) * 2 + ks) * 512 + lane * 8];
                int ntg = (n0 >> 4) + wn + t;
                size_t fb = ((size_t)(ntg * (Kp >> 5) + (kglob >> 5))) * 512 + lane * 8;
                bh[t] = *(const short8*)&Bhi[fb];
                bl[t] = *(const short8*)&Blo[fb];
            }
#pragma unroll
            for (int i = 0; i < 2; ++i)
#pragma unroll
                for (int j = 0; j < 2; ++j) {
                    acc[i][j] = __builtin_amdgcn_mfma_f32_16x16x32_bf16(ah[i], bh[j], acc[i][j], 0, 0, 0);
                    acc[i][j] = __builtin_amdgcn_mfma_f32_16x16x32_bf16(ah[i], bl[j], acc[i][j], 0, 0, 0);
                    acc[i][j] = __builtin_amdgcn_mfma_f32_16x16x32_bf16(al[i], bh[j], acc[i][j], 0, 0, 0);
                }
        }
        __syncthreads();
    }
    // ---- epilogue: C/D layout col=lane&15, row=quad*4+reg ----
    const int quad = lane >> 4;
    const int cl = lane & 15;
#pragma unroll
    for (int i = 0; i < 2; ++i) {
        int rbase = m0 + (wm + i) * 16 + quad * 4;
#pragma unroll
        for (int j = 0; j < 2; ++j) {
            int col = n0 + (wn + j) * 16 + cl;
            float bb = (MODE == 0) ? 0.f : bias[col];
#pragma unroll
            for (int r = 0; r < 4; ++r) {
                int row = rbase + r;
                if (row >= M) continue;
                if (MODE == 0) {
                    Out[(size_t)row * ldout + col] = acc[i][j][r];
                } else {
                    float h = acc[i][j][r] + bb;
                    if (MODE == 1) h = fmaxf(h, 0.f);
                    Out[(size_t)row * ldout + col] += h;
                }
            }
        }
    }
}

// ---------------- attributed encoder pieces ----------------
__global__ void k_att(const float* __restrict__ att_feats, const float* __restrict__ W_enc,
                      const float* __restrict__ a_w, float* __restrict__ att_proj,
                      float* __restrict__ att_score) {
    int a = blockIdx.x;
    int j = threadIdx.x;
    __shared__ float row[DIM];
    __shared__ float red[DIM];
    float v = att_feats[a * DIM + j];
    row[j] = v;
    red[j] = v * a_w[DIM + j];
    __syncthreads();
    for (int s = 128; s > 0; s >>= 1) {
        if (j < s) red[j] += red[j + s];
        __syncthreads();
    }
    if (j == 0) att_score[a] = red[0];
    float acc = 0.f;
    for (int d = 0; d < DIM; ++d)
        acc += row[d] * W_enc[d * DIM + j];
    att_proj[a * DIM + j] = acc;
}

__global__ void k_ent_score(const float* __restrict__ ent, const float* __restrict__ a_w,
                            float* __restrict__ score) {
    int i = blockIdx.x;
    int j = threadIdx.x;
    __shared__ float red[DIM];
    red[j] = ent[(size_t)i * DIM + j] * a_w[j];
    __syncthreads();
    for (int s = 128; s > 0; s >>= 1) {
        if (j < s) red[j] += red[j + s];
        __syncthreads();
    }
    if (j == 0) score[i] = red[0];
}

// fused: edge weight + row_sum atomic + per-bucket rank allocation for CSR build
__global__ void k_edge_score(const int* __restrict__ triples, const float* __restrict__ ent_score,
                             const float* __restrict__ att_score, const float* __restrict__ a_b,
                             float* __restrict__ edge_w, float* __restrict__ row_sum,
                             int* __restrict__ cnt, int* __restrict__ rank, int e_attr) {
    int e = blockIdx.x * blockDim.x + threadIdx.x;
    if (e >= e_attr) return;
    int h = triples[e * 3 + 0];
    int att = triples[e * 3 + 2];
    float s = ent_score[h] + att_score[att] + a_b[0];
    s = (s >= 0.f) ? s : 0.2f * s;
    float w = expf(s);
    edge_w[e] = w;
    atomicAdd(&row_sum[h], w);
    rank[e] = atomicAdd(&cnt[h], 1);
}

// ---------------- CSR build: blocksum -> scan of blocksums -> final scan ----------------
__global__ void k_blocksum(const int* __restrict__ cnt, int* __restrict__ bsum, int n) {
    int i = blockIdx.x * 256 + threadIdx.x;
    int v = (i < n) ? cnt[i] : 0;
    __shared__ int red[256];
    red[threadIdx.x] = v;
    __syncthreads();
    for (int s = 128; s > 0; s >>= 1) {
        if (threadIdx.x < s) red[threadIdx.x] += red[threadIdx.x + s];
        __syncthreads();
    }
    if (threadIdx.x == 0) bsum[blockIdx.x] = red[0];
}

// single block; exclusive scan of nb (<=256) block sums, in place
__global__ void k_scan_bsum(int* __restrict__ bsum, int nb) {
    int t = threadIdx.x;
    int v = (t < nb) ? bsum[t] : 0;
    __shared__ int buf[256];
    buf[t] = v;
    __syncthreads();
    for (int s = 1; s < 256; s <<= 1) {
        int tv = (t >= s) ? buf[t - s] : 0;
        __syncthreads();
        buf[t] += tv;
        __syncthreads();
    }
    if (t < nb) bsum[t] = buf[t] - v;  // exclusive
}

__global__ void k_scan_final(const int* __restrict__ cnt, const int* __restrict__ bsum,
                             int* __restrict__ off, int n) {
    int b = blockIdx.x;
    int t = threadIdx.x;
    int i = b * 256 + t;
    int v = (i < n) ? cnt[i] : 0;
    __shared__ int buf[256];
    buf[t] = v;
    __syncthreads();
    for (int s = 1; s < 256; s <<= 1) {
        int tv = (t >= s) ? buf[t - s] : 0;
        __syncthreads();
        buf[t] += tv;
        __syncthreads();
    }
    if (i < n) off[i] = bsum[b] + buf[t] - v;  // exclusive
    if (i == n - 1) off[n] = bsum[b] + buf[t]; // total
}

__global__ void k_scatter(const int* __restrict__ triples, const int* __restrict__ rank,
                          const int* __restrict__ off, int* __restrict__ eidx, int e_attr) {
    int e = blockIdx.x * blockDim.x + threadIdx.x;
    if (e >= e_attr) return;
    int h = triples[e * 3 + 0];
    eidx[off[h] + rank[e]] = e;
}

// ---------------- gather-based edge aggregation, fused with elu(agg+ent) -> F ----------------
// one wave per entity; lane holds 4 contiguous floats (fx4) of the 256-dim row
__global__ void k_edge_agg_csr(const int* __restrict__ triples, const float* __restrict__ edge_w,
                               const float* __restrict__ row_sum, const int* __restrict__ off,
                               const int* __restrict__ eidx, const fx4* __restrict__ att_proj,
                               const fx4* __restrict__ val_proj, const fx4* __restrict__ ent,
                               fx4* __restrict__ F, int n) {
    int wave = threadIdx.x >> 6;
    int lane = threadIdx.x & 63;
    int h = blockIdx.x * 4 + wave;
    if (h >= n) return;
    int s = off[h], e = off[h + 1];
    fx4 acc = {};
    float inv = (e > s) ? 1.0f / row_sum[h] : 0.f;
    for (int j = s; j < e; ++j) {
        int ed = eidx[j];
        int val = triples[ed * 3 + 1];
        int att = triples[ed * 3 + 2];
        float p = edge_w[ed] * inv;
        acc += p * (att_proj[(size_t)att * 64 + lane] + val_proj[(size_t)val * 64 + lane]);
    }
    fx4 x = acc + ent[(size_t)h * 64 + lane];
    fx4 r;
#pragma unroll
    for (int c = 0; c < 4; ++c) r[c] = (x[c] > 0.f) ? x[c] : expm1f(x[c]);
    F[(size_t)h * 64 + lane] = r;
}

__global__ void k_deg(const int* __restrict__ rows, int n_edges, int n,
                      int* __restrict__ off, float* __restrict__ deg_inv) {
    int i = blockIdx.x * blockDim.x + threadIdx.x;
    if (i > n) return;
    int lo = 0, hi = n_edges;
    while (lo < hi) {
        int m = (lo + hi) >> 1;
        if (rows[m] < i) lo = m + 1; else hi = m;
    }
    off[i] = lo;
    if (i < n) {
        int lo2 = lo, hi2 = n_edges;
        while (lo2 < hi2) {
            int m = (lo2 + hi2) >> 1;
            if (rows[m] < i + 1) lo2 = m + 1; else hi2 = m;
        }
        int d = lo2 - lo;
        deg_inv[i] = 1.0f / (float)(d > 0 ? d : 1);
    }
}

// one wave per row, float4 lanes
__global__ void k_gcn_agg(const int* __restrict__ off, const int* __restrict__ cols,
                          const float* __restrict__ deg_inv, const fx4* __restrict__ F,
                          fx4* __restrict__ T, int n) {
    int wave = threadIdx.x >> 6;
    int lane = threadIdx.x & 63;
    int i = blockIdx.x * 4 + wave;
    if (i >= n) return;
    int s = off[i], e = off[i + 1];
    fx4 acc = {};
    for (int k = s; k < e; ++k) {
        int c = cols[k];
        acc += F[(size_t)c * 64 + lane];
    }
    T[(size_t)i * 64 + lane] = acc * deg_inv[i];
}

__global__ void k_norm_out(const float* __restrict__ F, float* __restrict__ out) {
    int i = blockIdx.x;
    int j = threadIdx.x;
    __shared__ float red[DIM];
    float v = F[(size_t)i * DIM + j];
    red[j] = v * v;
    __syncthreads();
    for (int s = 128; s > 0; s >>= 1) {
        if (j < s) red[j] += red[j + s];
        __syncthreads();
    }
    float sc = 1.0f / fmaxf(sqrtf(red[0]), 1e-12f);
    out[(size_t)i * DIM + j] = v * sc;
}

__global__ void k_gather(const int* __restrict__ seed, const float* __restrict__ full,
                         float* __restrict__ out) {
    int i = blockIdx.x;
    int j = threadIdx.x;
    out[(size_t)i * DIM + j] = full[(size_t)seed[i] * DIM + j];
}

extern "C" void kernel_launch(void* const* d_in, const int* in_sizes, int n_in,
                              void* d_out, int out_size, void* d_ws, size_t ws_size,
                              hipStream_t stream) {
    const int* seed_sr = (const int*)d_in[0];
    const int* seed_tg = (const int*)d_in[1];
    const int* tri_sr = (const int*)d_in[2];
    const int* tri_tg = (const int*)d_in[3];
    const int* rows_sr = (const int*)d_in[4];
    const int* cols_sr = (const int*)d_in[5];
    const int* rows_tg = (const int*)d_in[6];
    const int* cols_tg = (const int*)d_in[7];
    const float* att_feats = (const float*)d_in[8];
    const float* val_feats = (const float*)d_in[9];
    const float* ent_sr = (const float*)d_in[10];
    const float* ent_tg = (const float*)d_in[11];
    const float* a_w = (const float*)d_in[12];
    const float* a_b = (const float*)d_in[13];
    const float* W_enc = (const float*)d_in[14];
    const float* w1 = (const float*)d_in[15];
    const float* b1 = (const float*)d_in[16];
    const float* w2 = (const float*)d_in[17];
    const float* b2 = (const float*)d_in[18];

    const int N = in_sizes[10] / DIM;        // 50000
    const int n_att = in_sizes[8] / DIM;     // 1001
    const int n_val = in_sizes[9] / VAL_DIM; // 100000
    const int e_attr = in_sizes[2] / 3;      // 200000
    const int n_seed = in_sizes[0];          // 10000
    const int KpV = 320;                     // padded K for val gemm
    const int nb = (N + 255) / 256;          // scan blocks (196)

    char* p = (char*)d_ws;
    auto alloc = [&](size_t nbytes) -> void* {
        void* r = (void*)p;
        p += (nbytes + 255) & ~(size_t)255;
        return r;
    };
    float* val_proj = (float*)alloc(sizeof(float) * (size_t)n_val * DIM);
    float* att_proj = (float*)alloc(sizeof(float) * (size_t)n_att * DIM);
    float* att_score = (float*)alloc(sizeof(float) * (size_t)n_att);
    float* ent_score = (float*)alloc(sizeof(float) * (size_t)N);
    float* row_sum = (float*)alloc(sizeof(float) * (size_t)N);
    float* edge_w = (float*)alloc(sizeof(float) * (size_t)e_attr);
    float* deg_inv = (float*)alloc(sizeof(float) * (size_t)N);
    int* off = (int*)alloc(sizeof(int) * (size_t)(N + 1));       // adjacency CSR (k_deg)
    int* off_csr = (int*)alloc(sizeof(int) * (size_t)(N + 1));   // attr-triple CSR
    int* cnt = (int*)alloc(sizeof(int) * (size_t)N);
    int* rank = (int*)alloc(sizeof(int) * (size_t)e_attr);
    int* bsum = (int*)alloc(sizeof(int) * (size_t)nb);
    int* eidx = (int*)alloc(sizeof(int) * (size_t)e_attr);
    float* F = (float*)alloc(sizeof(float) * (size_t)N * DIM);
    float* T = (float*)alloc(sizeof(float) * (size_t)N * DIM);
    // bf16-split weights in B-frag order
    short* wencv_hi = (short*)alloc(sizeof(short) * (DIM / 16) * (KpV / 32) * 512);
    short* wencv_lo = (short*)alloc(sizeof(short) * (DIM / 16) * (KpV / 32) * 512);
    short* w1_hi = (short*)alloc(sizeof(short) * (DIM / 16) * (DIM / 32) * 512);
    short* w1_lo = (short*)alloc(sizeof(short) * (DIM / 16) * (DIM / 32) * 512);
    short* w2_hi = (short*)alloc(sizeof(short) * (DIM / 16) * (DIM / 32) * 512);
    short* w2_lo = (short*)alloc(sizeof(short) * (DIM / 16) * (DIM / 32) * 512);

    float* out = (float*)d_out;
    float* out_seed_arr[2] = { out, out + (size_t)n_seed * DIM };
    float* out_full_arr[2] = { out + (size_t)2 * n_seed * DIM,
                               out + (size_t)2 * n_seed * DIM + (size_t)N * DIM };

    // weight splits (once)
    {
        int tot_v = (DIM / 16) * (KpV / 32) * 64;
        k_split_b<<<(tot_v + 255) / 256, 256, 0, stream>>>(W_enc + (size_t)DIM * DIM, wencv_hi,
                                                           wencv_lo, VAL_DIM, KpV, DIM);
        int tot_w = (DIM / 16) * (DIM / 32) * 64;
        k_split_b<<<(tot_w + 255) / 256, 256, 0, stream>>>(w1, w1_hi, w1_lo, DIM, DIM, DIM);
        k_split_b<<<(tot_w + 255) / 256, 256, 0, stream>>>(w2, w2_hi, w2_lo, DIM, DIM, DIM);
    }

    k_att<<<n_att, DIM, 0, stream>>>(att_feats, W_enc, a_w, att_proj, att_score);
    // val_proj = val_feats @ W_enc[256:]
    {
        dim3 g((n_val + 63) / 64, DIM / 64);
        k_gemm<0><<<g, 256, 0, stream>>>(val_feats, wencv_hi, wencv_lo, nullptr, val_proj,
                                         n_val, VAL_DIM, KpV, DIM);
    }

    const int* tris[2] = { tri_sr, tri_tg };
    const float* ents[2] = { ent_sr, ent_tg };
    const int* rws[2] = { rows_sr, rows_tg };
    const int* cls[2] = { cols_sr, cols_tg };
    const int eadj[2] = { in_sizes[4], in_sizes[6] };
    const int* seeds[2] = { seed_sr, seed_tg };

    for (int s = 0; s < 2; ++s) {
        k_ent_score<<<N, DIM, 0, stream>>>(ents[s], a_w, ent_score);
        hipMemsetAsync(row_sum, 0, sizeof(float) * (size_t)N, stream);
        hipMemsetAsync(cnt, 0, sizeof(int) * (size_t)N, stream);
        k_edge_score<<<(e_attr + 255) / 256, 256, 0, stream>>>(tris[s], ent_score, att_score,
                                                               a_b, edge_w, row_sum, cnt, rank,
                                                               e_attr);
        // build CSR over attribute triples by head entity
        k_blocksum<<<nb, 256, 0, stream>>>(cnt, bsum, N);
        k_scan_bsum<<<1, 256, 0, stream>>>(bsum, nb);
        k_scan_final<<<nb, 256, 0, stream>>>(cnt, bsum, off_csr, N);
        k_scatter<<<(e_attr + 255) / 256, 256, 0, stream>>>(tris[s], rank, off_csr, eidx, e_attr);
        // gather-aggregate + fused elu(agg + ent) -> F  (replaces atomic scatter + k_elu_add)
        k_edge_agg_csr<<<(N + 3) / 4, 256, 0, stream>>>(tris[s], edge_w, row_sum, off_csr, eidx,
                                                        (const fx4*)att_proj, (const fx4*)val_proj,
                                                        (const fx4*)ents[s], (fx4*)F, N);
        k_deg<<<(N + 1 + 255) / 256, 256, 0, stream>>>(rws[s], eadj[s], N, off, deg_inv);
        dim3 gg((N + 63) / 64, DIM / 64);
        k_gcn_agg<<<(N + 3) / 4, 256, 0, stream>>>(off, cls[s], deg_inv, (const fx4*)F, (fx4*)T, N);
        k_gemm<1><<<gg, 256, 0, stream>>>(T, w1_hi, w1_lo, b1, F, N, DIM, DIM, DIM);
        k_gcn_agg<<<(N + 3) / 4, 256, 0, stream>>>(off, cls[s], deg_inv, (const fx4*)F, (fx4*)T, N);
        k_gemm<2><<<gg, 256, 0, stream>>>(T, w2_hi, w2_lo, b2, F, N, DIM, DIM, DIM);
        k_norm_out<<<N, DIM, 0, stream>>>(F, out_full_arr[s]);
        k_gather<<<n_seed, DIM, 0, stream>>>(seeds[s], out_full_arr[s], out_seed_arr[s]);
    }
}

// Round 2
// 1419.864 us; speedup vs baseline: 1.1867x; 1.0478x over previous
//
#include <hip/hip_runtime.h>
#include <math.h>

#define DIM 256
#define VAL_DIM 300

typedef __attribute__((ext_vector_type(8))) short short8;
typedef __attribute__((ext_vector_type(4))) float fx4;

__device__ __forceinline__ short f2bf(float x) {
    unsigned u = __float_as_uint(x);
    unsigned r = (u + 0x7fff + ((u >> 16) & 1)) >> 16;
    return (short)r;
}
__device__ __forceinline__ float bf2f(short h) {
    return __uint_as_float(((unsigned)(unsigned short)h) << 16);
}

// ---------------- split B (weights) into MFMA B-fragment order, hi/lo bf16 ----------------
// B-frag layout: lane holds B[k = kt*32 + (lane>>4)*8 + j][n = nt*16 + (lane&15)], j=0..7
// storage: frag_idx = nt*(Kp/32) + kt; addr = frag_idx*512 + lane*8 + j
__global__ void k_split_b(const float* __restrict__ W, short* __restrict__ Bhi,
                          short* __restrict__ Blo, int Kreal, int Kp, int Ncols) {
    int idx = blockIdx.x * 256 + threadIdx.x;
    int total = (Ncols / 16) * (Kp / 32) * 64;
    if (idx >= total) return;
    int lane = idx & 63;
    int kt = (idx >> 6) % (Kp / 32);
    int nt = (idx >> 6) / (Kp / 32);
    int n = nt * 16 + (lane & 15);
    int kbase = kt * 32 + ((lane >> 4) & 3) * 8;
    short h[8], l[8];
#pragma unroll
    for (int j = 0; j < 8; ++j) {
        int k = kbase + j;
        float x = (k < Kreal) ? W[(size_t)k * Ncols + n] : 0.f;
        short hh = f2bf(x);
        float r = x - bf2f(hh);
        h[j] = hh;
        l[j] = f2bf(r);
    }
    size_t base = (size_t)idx * 8;
#pragma unroll
    for (int j = 0; j < 8; ++j) { Bhi[base + j] = h[j]; Blo[base + j] = l[j]; }
}

// ---------------- split-bf16 MFMA GEMM: Out = A(MxK fp32) @ B(Kx256 via frags) ----------------
// One block = 64 rows x 256 cols (full N stripe): A panel read exactly once.
// 512 threads = 8 waves arranged 2(m) x 4(n); each wave owns 32x64 (acc[2][4]).
// MODE 0: Out[row*256+col] = acc          (val_proj)
// MODE 1: Out += relu(acc + bias)         (gcn layer 1)
// MODE 2: Out += (acc + bias)             (gcn layer 2)
template <int MODE>
__global__ void k_gemm(const float* __restrict__ A, const short* __restrict__ Bhi,
                       const short* __restrict__ Blo, const float* __restrict__ bias,
                       float* __restrict__ Out, int M, int K, int Kp) {
    __shared__ short Ah[8 * 512];  // 8 subtiles (mt 0..3, ks 0..1) of 512 bf16 = 8KB
    __shared__ short Al[8 * 512];
    const int m0 = blockIdx.x * 64;
    const int tid = threadIdx.x;
    const int wave = tid >> 6;
    const int lane = tid & 63;
    const int wm = wave >> 2;        // 0..1 -> mtiles wm*2 + {0,1}
    const int wn = wave & 3;         // 0..3 -> ntiles wn*4 + {0..3}
    fx4 acc[2][4] = {};

    for (int pk = 0; pk < Kp; pk += 64) {
        // ---- stage A panel (64 rows x 64 k) as hi/lo fragments; one pass of 512 threads ----
        {
            int ss = tid;               // 0..511
            int mt = ss >> 7;           // 0..3
            int ks = (ss >> 6) & 1;     // 0..1
            int ln = ss & 63;
            int row = m0 + mt * 16 + (ln & 15);
            int kk = pk + ks * 32 + ((ln >> 4) & 3) * 8;
            float v[8];
            if (row < M && kk + 8 <= K) {
                fx4 u0 = *(const fx4*)&A[(size_t)row * K + kk];
                fx4 u1 = *(const fx4*)&A[(size_t)row * K + kk + 4];
                v[0] = u0[0]; v[1] = u0[1]; v[2] = u0[2]; v[3] = u0[3];
                v[4] = u1[0]; v[5] = u1[1]; v[6] = u1[2]; v[7] = u1[3];
            } else {
#pragma unroll
                for (int j = 0; j < 8; ++j)
                    v[j] = (row < M && kk + j < K) ? A[(size_t)row * K + kk + j] : 0.f;
            }
            short8 h8, l8;
#pragma unroll
            for (int j = 0; j < 8; ++j) {
                short hh = f2bf(v[j]);
                h8[j] = hh;
                l8[j] = f2bf(v[j] - bf2f(hh));
            }
            *(short8*)&Ah[(mt * 2 + ks) * 512 + ln * 8] = h8;
            *(short8*)&Al[(mt * 2 + ks) * 512 + ln * 8] = l8;
        }
        __syncthreads();
        // ---- compute: 2 MFMA k-steps of 32 ----
#pragma unroll
        for (int ks = 0; ks < 2; ++ks) {
            int kglob = pk + ks * 32;
            short8 ah[2], al[2], bh[4], bl[4];
#pragma unroll
            for (int t = 0; t < 2; ++t) {
                ah[t] = *(short8*)&Ah[((wm * 2 + t) * 2 + ks) * 512 + lane * 8];
                al[t] = *(short8*)&Al[((wm * 2 + t) * 2 + ks) * 512 + lane * 8];
            }
#pragma unroll
            for (int t = 0; t < 4; ++t) {
                int ntg = wn * 4 + t;
                size_t fb = ((size_t)(ntg * (Kp >> 5) + (kglob >> 5))) * 512 + lane * 8;
                bh[t] = *(const short8*)&Bhi[fb];
                bl[t] = *(const short8*)&Blo[fb];
            }
#pragma unroll
            for (int i = 0; i < 2; ++i)
#pragma unroll
                for (int j = 0; j < 4; ++j) {
                    acc[i][j] = __builtin_amdgcn_mfma_f32_16x16x32_bf16(ah[i], bh[j], acc[i][j], 0, 0, 0);
                    acc[i][j] = __builtin_amdgcn_mfma_f32_16x16x32_bf16(ah[i], bl[j], acc[i][j], 0, 0, 0);
                    acc[i][j] = __builtin_amdgcn_mfma_f32_16x16x32_bf16(al[i], bh[j], acc[i][j], 0, 0, 0);
                }
        }
        __syncthreads();
    }
    // ---- epilogue: C/D layout col=lane&15, row=quad*4+reg ----
    const int quad = lane >> 4;
    const int cl = lane & 15;
#pragma unroll
    for (int i = 0; i < 2; ++i) {
        int rbase = m0 + (wm * 2 + i) * 16 + quad * 4;
#pragma unroll
        for (int j = 0; j < 4; ++j) {
            int col = (wn * 4 + j) * 16 + cl;
            float bb = (MODE == 0) ? 0.f : bias[col];
#pragma unroll
            for (int r = 0; r < 4; ++r) {
                int row = rbase + r;
                if (row >= M) continue;
                if (MODE == 0) {
                    Out[(size_t)row * DIM + col] = acc[i][j][r];
                } else {
                    float h = acc[i][j][r] + bb;
                    if (MODE == 1) h = fmaxf(h, 0.f);
                    Out[(size_t)row * DIM + col] += h;
                }
            }
        }
    }
}

// ---------------- attributed encoder pieces ----------------
__global__ void k_att(const float* __restrict__ att_feats, const float* __restrict__ W_enc,
                      const float* __restrict__ a_w, float* __restrict__ att_proj,
                      float* __restrict__ att_score) {
    int a = blockIdx.x;
    int j = threadIdx.x;
    __shared__ float row[DIM];
    __shared__ float red[DIM];
    float v = att_feats[a * DIM + j];
    row[j] = v;
    red[j] = v * a_w[DIM + j];
    __syncthreads();
    for (int s = 128; s > 0; s >>= 1) {
        if (j < s) red[j] += red[j + s];
        __syncthreads();
    }
    if (j == 0) att_score[a] = red[0];
    float acc = 0.f;
    for (int d = 0; d < DIM; ++d)
        acc += row[d] * W_enc[d * DIM + j];
    att_proj[a * DIM + j] = acc;
}

__global__ void k_ent_score(const float* __restrict__ ent, const float* __restrict__ a_w,
                            float* __restrict__ score) {
    int i = blockIdx.x;
    int j = threadIdx.x;
    __shared__ float red[DIM];
    red[j] = ent[(size_t)i * DIM + j] * a_w[j];
    __syncthreads();
    for (int s = 128; s > 0; s >>= 1) {
        if (j < s) red[j] += red[j + s];
        __syncthreads();
    }
    if (j == 0) score[i] = red[0];
}

// fused: edge weight + row_sum atomic + per-bucket rank allocation for CSR build
__global__ void k_edge_score(const int* __restrict__ triples, const float* __restrict__ ent_score,
                             const float* __restrict__ att_score, const float* __restrict__ a_b,
                             float* __restrict__ edge_w, float* __restrict__ row_sum,
                             int* __restrict__ cnt, int* __restrict__ rank, int e_attr) {
    int e = blockIdx.x * blockDim.x + threadIdx.x;
    if (e >= e_attr) return;
    int h = triples[e * 3 + 0];
    int att = triples[e * 3 + 2];
    float s = ent_score[h] + att_score[att] + a_b[0];
    s = (s >= 0.f) ? s : 0.2f * s;
    float w = expf(s);
    edge_w[e] = w;
    atomicAdd(&row_sum[h], w);
    rank[e] = atomicAdd(&cnt[h], 1);
}

// ---------------- CSR build: blocksum -> scan of blocksums -> final scan ----------------
__global__ void k_blocksum(const int* __restrict__ cnt, int* __restrict__ bsum, int n) {
    int i = blockIdx.x * 256 + threadIdx.x;
    int v = (i < n) ? cnt[i] : 0;
    __shared__ int red[256];
    red[threadIdx.x] = v;
    __syncthreads();
    for (int s = 128; s > 0; s >>= 1) {
        if (threadIdx.x < s) red[threadIdx.x] += red[threadIdx.x + s];
        __syncthreads();
    }
    if (threadIdx.x == 0) bsum[blockIdx.x] = red[0];
}

// single block; exclusive scan of nb (<=256) block sums, in place
__global__ void k_scan_bsum(int* __restrict__ bsum, int nb) {
    int t = threadIdx.x;
    int v = (t < nb) ? bsum[t] : 0;
    __shared__ int buf[256];
    buf[t] = v;
    __syncthreads();
    for (int s = 1; s < 256; s <<= 1) {
        int tv = (t >= s) ? buf[t - s] : 0;
        __syncthreads();
        buf[t] += tv;
        __syncthreads();
    }
    if (t < nb) bsum[t] = buf[t] - v;  // exclusive
}

__global__ void k_scan_final(const int* __restrict__ cnt, const int* __restrict__ bsum,
                             int* __restrict__ off, int n) {
    int b = blockIdx.x;
    int t = threadIdx.x;
    int i = b * 256 + t;
    int v = (i < n) ? cnt[i] : 0;
    __shared__ int buf[256];
    buf[t] = v;
    __syncthreads();
    for (int s = 1; s < 256; s <<= 1) {
        int tv = (t >= s) ? buf[t - s] : 0;
        __syncthreads();
        buf[t] += tv;
        __syncthreads();
    }
    if (i < n) off[i] = bsum[b] + buf[t] - v;  // exclusive
    if (i == n - 1) off[n] = bsum[b] + buf[t]; // total
}

__global__ void k_scatter(const int* __restrict__ triples, const int* __restrict__ rank,
                          const int* __restrict__ off, int* __restrict__ eidx, int e_attr) {
    int e = blockIdx.x * blockDim.x + threadIdx.x;
    if (e >= e_attr) return;
    int h = triples[e * 3 + 0];
    eidx[off[h] + rank[e]] = e;
}

// ---------------- gather-based edge aggregation, fused with elu(agg+ent) -> F ----------------
// one wave per entity; lane holds 4 contiguous floats (fx4) of the 256-dim row
__global__ void k_edge_agg_csr(const int* __restrict__ triples, const float* __restrict__ edge_w,
                               const float* __restrict__ row_sum, const int* __restrict__ off,
                               const int* __restrict__ eidx, const fx4* __restrict__ att_proj,
                               const fx4* __restrict__ val_proj, const fx4* __restrict__ ent,
                               fx4* __restrict__ F, int n) {
    int wave = threadIdx.x >> 6;
    int lane = threadIdx.x & 63;
    int h = blockIdx.x * 4 + wave;
    if (h >= n) return;
    int s = off[h], e = off[h + 1];
    fx4 acc = {};
    float inv = (e > s) ? 1.0f / row_sum[h] : 0.f;
    for (int j = s; j < e; ++j) {
        int ed = eidx[j];
        int val = triples[ed * 3 + 1];
        int att = triples[ed * 3 + 2];
        float p = edge_w[ed] * inv;
        acc += p * (att_proj[(size_t)att * 64 + lane] + val_proj[(size_t)val * 64 + lane]);
    }
    fx4 x = acc + ent[(size_t)h * 64 + lane];
    fx4 r;
#pragma unroll
    for (int c = 0; c < 4; ++c) r[c] = (x[c] > 0.f) ? x[c] : expm1f(x[c]);
    F[(size_t)h * 64 + lane] = r;
}

__global__ void k_deg(const int* __restrict__ rows, int n_edges, int n,
                      int* __restrict__ off, float* __restrict__ deg_inv) {
    int i = blockIdx.x * blockDim.x + threadIdx.x;
    if (i > n) return;
    int lo = 0, hi = n_edges;
    while (lo < hi) {
        int m = (lo + hi) >> 1;
        if (rows[m] < i) lo = m + 1; else hi = m;
    }
    off[i] = lo;
    if (i < n) {
        int lo2 = lo, hi2 = n_edges;
        while (lo2 < hi2) {
            int m = (lo2 + hi2) >> 1;
            if (rows[m] < i + 1) lo2 = m + 1; else hi2 = m;
        }
        int d = lo2 - lo;
        deg_inv[i] = 1.0f / (float)(d > 0 ? d : 1);
    }
}

// one wave per row, float4 lanes
__global__ void k_gcn_agg(const int* __restrict__ off, const int* __restrict__ cols,
                          const float* __restrict__ deg_inv, const fx4* __restrict__ F,
                          fx4* __restrict__ T, int n) {
    int wave = threadIdx.x >> 6;
    int lane = threadIdx.x & 63;
    int i = blockIdx.x * 4 + wave;
    if (i >= n) return;
    int s = off[i], e = off[i + 1];
    fx4 acc = {};
    for (int k = s; k < e; ++k) {
        int c = cols[k];
        acc += F[(size_t)c * 64 + lane];
    }
    T[(size_t)i * 64 + lane] = acc * deg_inv[i];
}

__global__ void k_norm_out(const float* __restrict__ F, float* __restrict__ out) {
    int i = blockIdx.x;
    int j = threadIdx.x;
    __shared__ float red[DIM];
    float v = F[(size_t)i * DIM + j];
    red[j] = v * v;
    __syncthreads();
    for (int s = 128; s > 0; s >>= 1) {
        if (j < s) red[j] += red[j + s];
        __syncthreads();
    }
    float sc = 1.0f / fmaxf(sqrtf(red[0]), 1e-12f);
    out[(size_t)i * DIM + j] = v * sc;
}

__global__ void k_gather(const int* __restrict__ seed, const float* __restrict__ full,
                         float* __restrict__ out) {
    int i = blockIdx.x;
    int j = threadIdx.x;
    out[(size_t)i * DIM + j] = full[(size_t)seed[i] * DIM + j];
}

extern "C" void kernel_launch(void* const* d_in, const int* in_sizes, int n_in,
                              void* d_out, int out_size, void* d_ws, size_t ws_size,
                              hipStream_t stream) {
    const int* seed_sr = (const int*)d_in[0];
    const int* seed_tg = (const int*)d_in[1];
    const int* tri_sr = (const int*)d_in[2];
    const int* tri_tg = (const int*)d_in[3];
    const int* rows_sr = (const int*)d_in[4];
    const int* cols_sr = (const int*)d_in[5];
    const int* rows_tg = (const int*)d_in[6];
    const int* cols_tg = (const int*)d_in[7];
    const float* att_feats = (const float*)d_in[8];
    const float* val_feats = (const float*)d_in[9];
    const float* ent_sr = (const float*)d_in[10];
    const float* ent_tg = (const float*)d_in[11];
    const float* a_w = (const float*)d_in[12];
    const float* a_b = (const float*)d_in[13];
    const float* W_enc = (const float*)d_in[14];
    const float* w1 = (const float*)d_in[15];
    const float* b1 = (const float*)d_in[16];
    const float* w2 = (const float*)d_in[17];
    const float* b2 = (const float*)d_in[18];

    const int N = in_sizes[10] / DIM;        // 50000
    const int n_att = in_sizes[8] / DIM;     // 1001
    const int n_val = in_sizes[9] / VAL_DIM; // 100000
    const int e_attr = in_sizes[2] / 3;      // 200000
    const int n_seed = in_sizes[0];          // 10000
    const int KpV = 320;                     // padded K for val gemm
    const int nb = (N + 255) / 256;          // scan blocks (196)

    char* p = (char*)d_ws;
    auto alloc = [&](size_t nbytes) -> void* {
        void* r = (void*)p;
        p += (nbytes + 255) & ~(size_t)255;
        return r;
    };
    float* val_proj = (float*)alloc(sizeof(float) * (size_t)n_val * DIM);
    float* att_proj = (float*)alloc(sizeof(float) * (size_t)n_att * DIM);
    float* att_score = (float*)alloc(sizeof(float) * (size_t)n_att);
    float* ent_score = (float*)alloc(sizeof(float) * (size_t)N);
    float* row_sum = (float*)alloc(sizeof(float) * (size_t)N);
    float* edge_w = (float*)alloc(sizeof(float) * (size_t)e_attr);
    float* deg_inv = (float*)alloc(sizeof(float) * (size_t)N);
    int* off = (int*)alloc(sizeof(int) * (size_t)(N + 1));       // adjacency CSR (k_deg)
    int* off_csr = (int*)alloc(sizeof(int) * (size_t)(N + 1));   // attr-triple CSR
    int* cnt = (int*)alloc(sizeof(int) * (size_t)N);
    int* rank = (int*)alloc(sizeof(int) * (size_t)e_attr);
    int* bsum = (int*)alloc(sizeof(int) * (size_t)nb);
    int* eidx = (int*)alloc(sizeof(int) * (size_t)e_attr);
    float* F = (float*)alloc(sizeof(float) * (size_t)N * DIM);
    float* T = (float*)alloc(sizeof(float) * (size_t)N * DIM);
    // bf16-split weights in B-frag order
    short* wencv_hi = (short*)alloc(sizeof(short) * (DIM / 16) * (KpV / 32) * 512);
    short* wencv_lo = (short*)alloc(sizeof(short) * (DIM / 16) * (KpV / 32) * 512);
    short* w1_hi = (short*)alloc(sizeof(short) * (DIM / 16) * (DIM / 32) * 512);
    short* w1_lo = (short*)alloc(sizeof(short) * (DIM / 16) * (DIM / 32) * 512);
    short* w2_hi = (short*)alloc(sizeof(short) * (DIM / 16) * (DIM / 32) * 512);
    short* w2_lo = (short*)alloc(sizeof(short) * (DIM / 16) * (DIM / 32) * 512);

    float* out = (float*)d_out;
    float* out_seed_arr[2] = { out, out + (size_t)n_seed * DIM };
    float* out_full_arr[2] = { out + (size_t)2 * n_seed * DIM,
                               out + (size_t)2 * n_seed * DIM + (size_t)N * DIM };

    // weight splits (once)
    {
        int tot_v = (DIM / 16) * (KpV / 32) * 64;
        k_split_b<<<(tot_v + 255) / 256, 256, 0, stream>>>(W_enc + (size_t)DIM * DIM, wencv_hi,
                                                           wencv_lo, VAL_DIM, KpV, DIM);
        int tot_w = (DIM / 16) * (DIM / 32) * 64;
        k_split_b<<<(tot_w + 255) / 256, 256, 0, stream>>>(w1, w1_hi, w1_lo, DIM, DIM, DIM);
        k_split_b<<<(tot_w + 255) / 256, 256, 0, stream>>>(w2, w2_hi, w2_lo, DIM, DIM, DIM);
    }

    k_att<<<n_att, DIM, 0, stream>>>(att_feats, W_enc, a_w, att_proj, att_score);
    // val_proj = val_feats @ W_enc[256:]
    k_gemm<0><<<(n_val + 63) / 64, 512, 0, stream>>>(val_feats, wencv_hi, wencv_lo, nullptr,
                                                     val_proj, n_val, VAL_DIM, KpV);

    const int* tris[2] = { tri_sr, tri_tg };
    const float* ents[2] = { ent_sr, ent_tg };
    const int* rws[2] = { rows_sr, rows_tg };
    const int* cls[2] = { cols_sr, cols_tg };
    const int eadj[2] = { in_sizes[4], in_sizes[6] };
    const int* seeds[2] = { seed_sr, seed_tg };

    for (int s = 0; s < 2; ++s) {
        k_ent_score<<<N, DIM, 0, stream>>>(ents[s], a_w, ent_score);
        hipMemsetAsync(row_sum, 0, sizeof(float) * (size_t)N, stream);
        hipMemsetAsync(cnt, 0, sizeof(int) * (size_t)N, stream);
        k_edge_score<<<(e_attr + 255) / 256, 256, 0, stream>>>(tris[s], ent_score, att_score,
                                                               a_b, edge_w, row_sum, cnt, rank,
                                                               e_attr);
        // build CSR over attribute triples by head entity
        k_blocksum<<<nb, 256, 0, stream>>>(cnt, bsum, N);
        k_scan_bsum<<<1, 256, 0, stream>>>(bsum, nb);
        k_scan_final<<<nb, 256, 0, stream>>>(cnt, bsum, off_csr, N);
        k_scatter<<<(e_attr + 255) / 256, 256, 0, stream>>>(tris[s], rank, off_csr, eidx, e_attr);
        // gather-aggregate + fused elu(agg + ent) -> F  (replaces atomic scatter + k_elu_add)
        k_edge_agg_csr<<<(N + 3) / 4, 256, 0, stream>>>(tris[s], edge_w, row_sum, off_csr, eidx,
                                                        (const fx4*)att_proj, (const fx4*)val_proj,
                                                        (const fx4*)ents[s], (fx4*)F, N);
        k_deg<<<(N + 1 + 255) / 256, 256, 0, stream>>>(rws[s], eadj[s], N, off, deg_inv);
        k_gcn_agg<<<(N + 3) / 4, 256, 0, stream>>>(off, cls[s], deg_inv, (const fx4*)F, (fx4*)T, N);
        k_gemm<1><<<(N + 63) / 64, 512, 0, stream>>>(T, w1_hi, w1_lo, b1, F, N, DIM, DIM);
        k_gcn_agg<<<(N + 3) / 4, 256, 0, stream>>>(off, cls[s], deg_inv, (const fx4*)F, (fx4*)T, N);
        k_gemm<2><<<(N + 63) / 64, 512, 0, stream>>>(T, w2_hi, w2_lo, b2, F, N, DIM, DIM);
        k_norm_out<<<N, DIM, 0, stream>>>(F, out_full_arr[s]);
        k_gather<<<n_seed, DIM, 0, stream>>>(seeds[s], out_full_arr[s], out_seed_arr[s]);
    }
}

// Round 3
// 1174.483 us; speedup vs baseline: 1.4346x; 1.2089x over previous
//
#include <hip/hip_runtime.h>
#include <math.h>

#define DIM 256
#define VAL_DIM 300

typedef __attribute__((ext_vector_type(8))) short short8;
typedef __attribute__((ext_vector_type(4))) float fx4;
typedef _Float16 f16;
typedef __attribute__((ext_vector_type(4))) _Float16 h4;

__device__ __forceinline__ short f2bf(float x) {
    unsigned u = __float_as_uint(x);
    unsigned r = (u + 0x7fff + ((u >> 16) & 1)) >> 16;
    return (short)r;
}
__device__ __forceinline__ float bf2f(short h) {
    return __uint_as_float(((unsigned)(unsigned short)h) << 16);
}

// ---------------- split B (weights) into MFMA B-fragment order, hi/lo bf16 ----------------
// B-frag layout: lane holds B[k = kt*32 + (lane>>4)*8 + j][n = nt*16 + (lane&15)], j=0..7
// storage: frag_idx = nt*(Kp/32) + kt; addr = frag_idx*512 + lane*8 + j
__global__ void k_split_b(const float* __restrict__ W, short* __restrict__ Bhi,
                          short* __restrict__ Blo, int Kreal, int Kp, int Ncols) {
    int idx = blockIdx.x * 256 + threadIdx.x;
    int total = (Ncols / 16) * (Kp / 32) * 64;
    if (idx >= total) return;
    int lane = idx & 63;
    int kt = (idx >> 6) % (Kp / 32);
    int nt = (idx >> 6) / (Kp / 32);
    int n = nt * 16 + (lane & 15);
    int kbase = kt * 32 + ((lane >> 4) & 3) * 8;
    short h[8], l[8];
#pragma unroll
    for (int j = 0; j < 8; ++j) {
        int k = kbase + j;
        float x = (k < Kreal) ? W[(size_t)k * Ncols + n] : 0.f;
        short hh = f2bf(x);
        float r = x - bf2f(hh);
        h[j] = hh;
        l[j] = f2bf(r);
    }
    size_t base = (size_t)idx * 8;
#pragma unroll
    for (int j = 0; j < 8; ++j) { Bhi[base + j] = h[j]; Blo[base + j] = l[j]; }
}

// ---------------- split-bf16 MFMA GEMM: Out = A(MxK fp32) @ B(Kx256 via frags) ----------------
// One block = 64 rows x 256 cols (full N stripe): A panel read exactly once.
// 512 threads = 8 waves arranged 2(m) x 4(n); each wave owns 32x64 (acc[2][4]).
// MODE 0: Out16[row*256+col] = (f16)acc                  (val_proj, fp16-only output)
// MODE 1: v = Out + relu(acc+bias); Out = v; Out16 = v   (gcn layer 1)
// MODE 2: Out += (acc + bias)                            (gcn layer 2)
template <int MODE>
__global__ void k_gemm(const float* __restrict__ A, const short* __restrict__ Bhi,
                       const short* __restrict__ Blo, const float* __restrict__ bias,
                       float* __restrict__ Out, f16* __restrict__ Out16, int M, int K, int Kp) {
    __shared__ short Ah[8 * 512];  // 8 subtiles (mt 0..3, ks 0..1) of 512 bf16 = 8KB
    __shared__ short Al[8 * 512];
    const int m0 = blockIdx.x * 64;
    const int tid = threadIdx.x;
    const int wave = tid >> 6;
    const int lane = tid & 63;
    const int wm = wave >> 2;        // 0..1 -> mtiles wm*2 + {0,1}
    const int wn = wave & 3;         // 0..3 -> ntiles wn*4 + {0..3}
    fx4 acc[2][4] = {};

    for (int pk = 0; pk < Kp; pk += 64) {
        // ---- stage A panel (64 rows x 64 k) as hi/lo fragments; one pass of 512 threads ----
        {
            int ss = tid;               // 0..511
            int mt = ss >> 7;           // 0..3
            int ks = (ss >> 6) & 1;     // 0..1
            int ln = ss & 63;
            int row = m0 + mt * 16 + (ln & 15);
            int kk = pk + ks * 32 + ((ln >> 4) & 3) * 8;
            float v[8];
            if (row < M && kk + 8 <= K) {
                fx4 u0 = *(const fx4*)&A[(size_t)row * K + kk];
                fx4 u1 = *(const fx4*)&A[(size_t)row * K + kk + 4];
                v[0] = u0[0]; v[1] = u0[1]; v[2] = u0[2]; v[3] = u0[3];
                v[4] = u1[0]; v[5] = u1[1]; v[6] = u1[2]; v[7] = u1[3];
            } else {
#pragma unroll
                for (int j = 0; j < 8; ++j)
                    v[j] = (row < M && kk + j < K) ? A[(size_t)row * K + kk + j] : 0.f;
            }
            short8 h8, l8;
#pragma unroll
            for (int j = 0; j < 8; ++j) {
                short hh = f2bf(v[j]);
                h8[j] = hh;
                l8[j] = f2bf(v[j] - bf2f(hh));
            }
            *(short8*)&Ah[(mt * 2 + ks) * 512 + ln * 8] = h8;
            *(short8*)&Al[(mt * 2 + ks) * 512 + ln * 8] = l8;
        }
        __syncthreads();
        // ---- compute: 2 MFMA k-steps of 32 ----
#pragma unroll
        for (int ks = 0; ks < 2; ++ks) {
            int kglob = pk + ks * 32;
            short8 ah[2], al[2], bh[4], bl[4];
#pragma unroll
            for (int t = 0; t < 2; ++t) {
                ah[t] = *(short8*)&Ah[((wm * 2 + t) * 2 + ks) * 512 + lane * 8];
                al[t] = *(short8*)&Al[((wm * 2 + t) * 2 + ks) * 512 + lane * 8];
            }
#pragma unroll
            for (int t = 0; t < 4; ++t) {
                int ntg = wn * 4 + t;
                size_t fb = ((size_t)(ntg * (Kp >> 5) + (kglob >> 5))) * 512 + lane * 8;
                bh[t] = *(const short8*)&Bhi[fb];
                bl[t] = *(const short8*)&Blo[fb];
            }
#pragma unroll
            for (int i = 0; i < 2; ++i)
#pragma unroll
                for (int j = 0; j < 4; ++j) {
                    acc[i][j] = __builtin_amdgcn_mfma_f32_16x16x32_bf16(ah[i], bh[j], acc[i][j], 0, 0, 0);
                    acc[i][j] = __builtin_amdgcn_mfma_f32_16x16x32_bf16(ah[i], bl[j], acc[i][j], 0, 0, 0);
                    acc[i][j] = __builtin_amdgcn_mfma_f32_16x16x32_bf16(al[i], bh[j], acc[i][j], 0, 0, 0);
                }
        }
        __syncthreads();
    }
    // ---- epilogue: C/D layout col=lane&15, row=quad*4+reg ----
    const int quad = lane >> 4;
    const int cl = lane & 15;
#pragma unroll
    for (int i = 0; i < 2; ++i) {
        int rbase = m0 + (wm * 2 + i) * 16 + quad * 4;
#pragma unroll
        for (int j = 0; j < 4; ++j) {
            int col = (wn * 4 + j) * 16 + cl;
            float bb = (MODE == 0) ? 0.f : bias[col];
#pragma unroll
            for (int r = 0; r < 4; ++r) {
                int row = rbase + r;
                if (row >= M) continue;
                size_t idx = (size_t)row * DIM + col;
                if (MODE == 0) {
                    Out16[idx] = (f16)acc[i][j][r];
                } else if (MODE == 1) {
                    float h = fmaxf(acc[i][j][r] + bb, 0.f);
                    float v = Out[idx] + h;
                    Out[idx] = v;
                    Out16[idx] = (f16)v;
                } else {
                    Out[idx] += acc[i][j][r] + bb;
                }
            }
        }
    }
}

// ---------------- attributed encoder pieces ----------------
__global__ void k_att(const float* __restrict__ att_feats, const float* __restrict__ W_enc,
                      const float* __restrict__ a_w, float* __restrict__ att_proj,
                      float* __restrict__ att_score) {
    int a = blockIdx.x;
    int j = threadIdx.x;
    __shared__ float row[DIM];
    __shared__ float red[DIM];
    float v = att_feats[a * DIM + j];
    row[j] = v;
    red[j] = v * a_w[DIM + j];
    __syncthreads();
    for (int s = 128; s > 0; s >>= 1) {
        if (j < s) red[j] += red[j + s];
        __syncthreads();
    }
    if (j == 0) att_score[a] = red[0];
    float acc = 0.f;
    for (int d = 0; d < DIM; ++d)
        acc += row[d] * W_enc[d * DIM + j];
    att_proj[a * DIM + j] = acc;
}

__global__ void k_ent_score(const float* __restrict__ ent, const float* __restrict__ a_w,
                            float* __restrict__ score) {
    int i = blockIdx.x;
    int j = threadIdx.x;
    __shared__ float red[DIM];
    red[j] = ent[(size_t)i * DIM + j] * a_w[j];
    __syncthreads();
    for (int s = 128; s > 0; s >>= 1) {
        if (j < s) red[j] += red[j + s];
        __syncthreads();
    }
    if (j == 0) score[i] = red[0];
}

// fused: edge weight + row_sum atomic + per-bucket rank allocation for CSR build
__global__ void k_edge_score(const int* __restrict__ triples, const float* __restrict__ ent_score,
                             const float* __restrict__ att_score, const float* __restrict__ a_b,
                             float* __restrict__ edge_w, float* __restrict__ row_sum,
                             int* __restrict__ cnt, int* __restrict__ rank, int e_attr) {
    int e = blockIdx.x * blockDim.x + threadIdx.x;
    if (e >= e_attr) return;
    int h = triples[e * 3 + 0];
    int att = triples[e * 3 + 2];
    float s = ent_score[h] + att_score[att] + a_b[0];
    s = (s >= 0.f) ? s : 0.2f * s;
    float w = expf(s);
    edge_w[e] = w;
    atomicAdd(&row_sum[h], w);
    rank[e] = atomicAdd(&cnt[h], 1);
}

// ---------------- CSR build: blocksum -> scan of blocksums -> final scan ----------------
__global__ void k_blocksum(const int* __restrict__ cnt, int* __restrict__ bsum, int n) {
    int i = blockIdx.x * 256 + threadIdx.x;
    int v = (i < n) ? cnt[i] : 0;
    __shared__ int red[256];
    red[threadIdx.x] = v;
    __syncthreads();
    for (int s = 128; s > 0; s >>= 1) {
        if (threadIdx.x < s) red[threadIdx.x] += red[threadIdx.x + s];
        __syncthreads();
    }
    if (threadIdx.x == 0) bsum[blockIdx.x] = red[0];
}

// single block; exclusive scan of nb (<=256) block sums, in place
__global__ void k_scan_bsum(int* __restrict__ bsum, int nb) {
    int t = threadIdx.x;
    int v = (t < nb) ? bsum[t] : 0;
    __shared__ int buf[256];
    buf[t] = v;
    __syncthreads();
    for (int s = 1; s < 256; s <<= 1) {
        int tv = (t >= s) ? buf[t - s] : 0;
        __syncthreads();
        buf[t] += tv;
        __syncthreads();
    }
    if (t < nb) bsum[t] = buf[t] - v;  // exclusive
}

__global__ void k_scan_final(const int* __restrict__ cnt, const int* __restrict__ bsum,
                             int* __restrict__ off, int n) {
    int b = blockIdx.x;
    int t = threadIdx.x;
    int i = b * 256 + t;
    int v = (i < n) ? cnt[i] : 0;
    __shared__ int buf[256];
    buf[t] = v;
    __syncthreads();
    for (int s = 1; s < 256; s <<= 1) {
        int tv = (t >= s) ? buf[t - s] : 0;
        __syncthreads();
        buf[t] += tv;
        __syncthreads();
    }
    if (i < n) off[i] = bsum[b] + buf[t] - v;  // exclusive
    if (i == n - 1) off[n] = bsum[b] + buf[t]; // total
}

__global__ void k_scatter(const int* __restrict__ triples, const int* __restrict__ rank,
                          const int* __restrict__ off, int* __restrict__ eidx, int e_attr) {
    int e = blockIdx.x * blockDim.x + threadIdx.x;
    if (e >= e_attr) return;
    int h = triples[e * 3 + 0];
    eidx[off[h] + rank[e]] = e;
}

// ---------------- gather-based edge aggregation, fused with elu(agg+ent) -> F, F16 ----------------
// one wave per entity; lane holds 4 contiguous floats (fx4) of the 256-dim row
__global__ void k_edge_agg_csr(const int* __restrict__ triples, const float* __restrict__ edge_w,
                               const float* __restrict__ row_sum, const int* __restrict__ off,
                               const int* __restrict__ eidx, const fx4* __restrict__ att_proj,
                               const h4* __restrict__ val_proj, const fx4* __restrict__ ent,
                               fx4* __restrict__ F, h4* __restrict__ F16, int n) {
    int wave = threadIdx.x >> 6;
    int lane = threadIdx.x & 63;
    int h = blockIdx.x * 4 + wave;
    if (h >= n) return;
    int s = off[h], e = off[h + 1];
    fx4 acc = {};
    float inv = (e > s) ? 1.0f / row_sum[h] : 0.f;
    for (int j = s; j < e; ++j) {
        int ed = eidx[j];
        int val = triples[ed * 3 + 1];
        int att = triples[ed * 3 + 2];
        float p = edge_w[ed] * inv;
        fx4 a = att_proj[(size_t)att * 64 + lane];
        h4 v = val_proj[(size_t)val * 64 + lane];
#pragma unroll
        for (int c = 0; c < 4; ++c) acc[c] += p * (a[c] + (float)v[c]);
    }
    fx4 x = acc + ent[(size_t)h * 64 + lane];
    fx4 r;
    h4 r16;
#pragma unroll
    for (int c = 0; c < 4; ++c) {
        r[c] = (x[c] > 0.f) ? x[c] : expm1f(x[c]);
        r16[c] = (f16)r[c];
    }
    F[(size_t)h * 64 + lane] = r;
    F16[(size_t)h * 64 + lane] = r16;
}

__global__ void k_deg(const int* __restrict__ rows, int n_edges, int n,
                      int* __restrict__ off, float* __restrict__ deg_inv) {
    int i = blockIdx.x * blockDim.x + threadIdx.x;
    if (i > n) return;
    int lo = 0, hi = n_edges;
    while (lo < hi) {
        int m = (lo + hi) >> 1;
        if (rows[m] < i) lo = m + 1; else hi = m;
    }
    off[i] = lo;
    if (i < n) {
        int lo2 = lo, hi2 = n_edges;
        while (lo2 < hi2) {
            int m = (lo2 + hi2) >> 1;
            if (rows[m] < i + 1) lo2 = m + 1; else hi2 = m;
        }
        int d = lo2 - lo;
        deg_inv[i] = 1.0f / (float)(d > 0 ? d : 1);
    }
}

// one wave per row, fp16 gather (halved bytes), unroll-4 for outstanding loads
__global__ void k_gcn_agg(const int* __restrict__ off, const int* __restrict__ cols,
                          const float* __restrict__ deg_inv, const h4* __restrict__ F16,
                          fx4* __restrict__ T, int n) {
    int wave = threadIdx.x >> 6;
    int lane = threadIdx.x & 63;
    int i = blockIdx.x * 4 + wave;
    if (i >= n) return;
    int s = off[i], e = off[i + 1];
    fx4 acc = {};
    int k = s;
    for (; k + 4 <= e; k += 4) {
        int c0 = cols[k], c1 = cols[k + 1], c2 = cols[k + 2], c3 = cols[k + 3];
        h4 r0 = F16[(size_t)c0 * 64 + lane];
        h4 r1 = F16[(size_t)c1 * 64 + lane];
        h4 r2 = F16[(size_t)c2 * 64 + lane];
        h4 r3 = F16[(size_t)c3 * 64 + lane];
#pragma unroll
        for (int c = 0; c < 4; ++c)
            acc[c] += ((float)r0[c] + (float)r1[c]) + ((float)r2[c] + (float)r3[c]);
    }
    for (; k < e; ++k) {
        h4 r = F16[(size_t)cols[k] * 64 + lane];
#pragma unroll
        for (int c = 0; c < 4; ++c) acc[c] += (float)r[c];
    }
    T[(size_t)i * 64 + lane] = acc * deg_inv[i];
}

__global__ void k_norm_out(const float* __restrict__ F, float* __restrict__ out) {
    int i = blockIdx.x;
    int j = threadIdx.x;
    __shared__ float red[DIM];
    float v = F[(size_t)i * DIM + j];
    red[j] = v * v;
    __syncthreads();
    for (int s = 128; s > 0; s >>= 1) {
        if (j < s) red[j] += red[j + s];
        __syncthreads();
    }
    float sc = 1.0f / fmaxf(sqrtf(red[0]), 1e-12f);
    out[(size_t)i * DIM + j] = v * sc;
}

__global__ void k_gather(const int* __restrict__ seed, const float* __restrict__ full,
                         float* __restrict__ out) {
    int i = blockIdx.x;
    int j = threadIdx.x;
    out[(size_t)i * DIM + j] = full[(size_t)seed[i] * DIM + j];
}

extern "C" void kernel_launch(void* const* d_in, const int* in_sizes, int n_in,
                              void* d_out, int out_size, void* d_ws, size_t ws_size,
                              hipStream_t stream) {
    const int* seed_sr = (const int*)d_in[0];
    const int* seed_tg = (const int*)d_in[1];
    const int* tri_sr = (const int*)d_in[2];
    const int* tri_tg = (const int*)d_in[3];
    const int* rows_sr = (const int*)d_in[4];
    const int* cols_sr = (const int*)d_in[5];
    const int* rows_tg = (const int*)d_in[6];
    const int* cols_tg = (const int*)d_in[7];
    const float* att_feats = (const float*)d_in[8];
    const float* val_feats = (const float*)d_in[9];
    const float* ent_sr = (const float*)d_in[10];
    const float* ent_tg = (const float*)d_in[11];
    const float* a_w = (const float*)d_in[12];
    const float* a_b = (const float*)d_in[13];
    const float* W_enc = (const float*)d_in[14];
    const float* w1 = (const float*)d_in[15];
    const float* b1 = (const float*)d_in[16];
    const float* w2 = (const float*)d_in[17];
    const float* b2 = (const float*)d_in[18];

    const int N = in_sizes[10] / DIM;        // 50000
    const int n_att = in_sizes[8] / DIM;     // 1001
    const int n_val = in_sizes[9] / VAL_DIM; // 100000
    const int e_attr = in_sizes[2] / 3;      // 200000
    const int n_seed = in_sizes[0];          // 10000
    const int KpV = 320;                     // padded K for val gemm
    const int nb = (N + 255) / 256;          // scan blocks (196)

    char* p = (char*)d_ws;
    auto alloc = [&](size_t nbytes) -> void* {
        void* r = (void*)p;
        p += (nbytes + 255) & ~(size_t)255;
        return r;
    };
    f16* val16 = (f16*)alloc(sizeof(f16) * (size_t)n_val * DIM);
    float* att_proj = (float*)alloc(sizeof(float) * (size_t)n_att * DIM);
    float* att_score = (float*)alloc(sizeof(float) * (size_t)n_att);
    float* ent_score = (float*)alloc(sizeof(float) * (size_t)N);
    float* row_sum = (float*)alloc(sizeof(float) * (size_t)N);
    float* edge_w = (float*)alloc(sizeof(float) * (size_t)e_attr);
    float* deg_inv = (float*)alloc(sizeof(float) * (size_t)N);
    int* off = (int*)alloc(sizeof(int) * (size_t)(N + 1));       // adjacency CSR (k_deg)
    int* off_csr = (int*)alloc(sizeof(int) * (size_t)(N + 1));   // attr-triple CSR
    int* cnt = (int*)alloc(sizeof(int) * (size_t)N);
    int* rank = (int*)alloc(sizeof(int) * (size_t)e_attr);
    int* bsum = (int*)alloc(sizeof(int) * (size_t)nb);
    int* eidx = (int*)alloc(sizeof(int) * (size_t)e_attr);
    float* F = (float*)alloc(sizeof(float) * (size_t)N * DIM);
    f16* F16 = (f16*)alloc(sizeof(f16) * (size_t)N * DIM);
    float* T = (float*)alloc(sizeof(float) * (size_t)N * DIM);
    // bf16-split weights in B-frag order
    short* wencv_hi = (short*)alloc(sizeof(short) * (DIM / 16) * (KpV / 32) * 512);
    short* wencv_lo = (short*)alloc(sizeof(short) * (DIM / 16) * (KpV / 32) * 512);
    short* w1_hi = (short*)alloc(sizeof(short) * (DIM / 16) * (DIM / 32) * 512);
    short* w1_lo = (short*)alloc(sizeof(short) * (DIM / 16) * (DIM / 32) * 512);
    short* w2_hi = (short*)alloc(sizeof(short) * (DIM / 16) * (DIM / 32) * 512);
    short* w2_lo = (short*)alloc(sizeof(short) * (DIM / 16) * (DIM / 32) * 512);

    float* out = (float*)d_out;
    float* out_seed_arr[2] = { out, out + (size_t)n_seed * DIM };
    float* out_full_arr[2] = { out + (size_t)2 * n_seed * DIM,
                               out + (size_t)2 * n_seed * DIM + (size_t)N * DIM };

    // weight splits (once)
    {
        int tot_v = (DIM / 16) * (KpV / 32) * 64;
        k_split_b<<<(tot_v + 255) / 256, 256, 0, stream>>>(W_enc + (size_t)DIM * DIM, wencv_hi,
                                                           wencv_lo, VAL_DIM, KpV, DIM);
        int tot_w = (DIM / 16) * (DIM / 32) * 64;
        k_split_b<<<(tot_w + 255) / 256, 256, 0, stream>>>(w1, w1_hi, w1_lo, DIM, DIM, DIM);
        k_split_b<<<(tot_w + 255) / 256, 256, 0, stream>>>(w2, w2_hi, w2_lo, DIM, DIM, DIM);
    }

    k_att<<<n_att, DIM, 0, stream>>>(att_feats, W_enc, a_w, att_proj, att_score);
    // val_proj (fp16) = val_feats @ W_enc[256:]
    k_gemm<0><<<(n_val + 63) / 64, 512, 0, stream>>>(val_feats, wencv_hi, wencv_lo, nullptr,
                                                     nullptr, val16, n_val, VAL_DIM, KpV);

    const int* tris[2] = { tri_sr, tri_tg };
    const float* ents[2] = { ent_sr, ent_tg };
    const int* rws[2] = { rows_sr, rows_tg };
    const int* cls[2] = { cols_sr, cols_tg };
    const int eadj[2] = { in_sizes[4], in_sizes[6] };
    const int* seeds[2] = { seed_sr, seed_tg };

    for (int s = 0; s < 2; ++s) {
        k_ent_score<<<N, DIM, 0, stream>>>(ents[s], a_w, ent_score);
        hipMemsetAsync(row_sum, 0, sizeof(float) * (size_t)N, stream);
        hipMemsetAsync(cnt, 0, sizeof(int) * (size_t)N, stream);
        k_edge_score<<<(e_attr + 255) / 256, 256, 0, stream>>>(tris[s], ent_score, att_score,
                                                               a_b, edge_w, row_sum, cnt, rank,
                                                               e_attr);
        // build CSR over attribute triples by head entity
        k_blocksum<<<nb, 256, 0, stream>>>(cnt, bsum, N);
        k_scan_bsum<<<1, 256, 0, stream>>>(bsum, nb);
        k_scan_final<<<nb, 256, 0, stream>>>(cnt, bsum, off_csr, N);
        k_scatter<<<(e_attr + 255) / 256, 256, 0, stream>>>(tris[s], rank, off_csr, eidx, e_attr);
        // gather-aggregate + fused elu(agg + ent) -> F, F16
        k_edge_agg_csr<<<(N + 3) / 4, 256, 0, stream>>>(tris[s], edge_w, row_sum, off_csr, eidx,
                                                        (const fx4*)att_proj, (const h4*)val16,
                                                        (const fx4*)ents[s], (fx4*)F, (h4*)F16, N);
        k_deg<<<(N + 1 + 255) / 256, 256, 0, stream>>>(rws[s], eadj[s], N, off, deg_inv);
        k_gcn_agg<<<(N + 3) / 4, 256, 0, stream>>>(off, cls[s], deg_inv, (const h4*)F16, (fx4*)T, N);
        k_gemm<1><<<(N + 63) / 64, 512, 0, stream>>>(T, w1_hi, w1_lo, b1, F, F16, N, DIM, DIM);
        k_gcn_agg<<<(N + 3) / 4, 256, 0, stream>>>(off, cls[s], deg_inv, (const h4*)F16, (fx4*)T, N);
        k_gemm<2><<<(N + 63) / 64, 512, 0, stream>>>(T, w2_hi, w2_lo, b2, F, nullptr, N, DIM, DIM);
        k_norm_out<<<N, DIM, 0, stream>>>(F, out_full_arr[s]);
        k_gather<<<n_seed, DIM, 0, stream>>>(seeds[s], out_full_arr[s], out_seed_arr[s]);
    }
}